// Round 3
// baseline (852.384 us; speedup 1.0000x reference)
//
#include <hip/hip_runtime.h>
#include <cstdint>
#include <math.h>

// Transformer block: LN1 -> QKV -> fused MHA -> proj+res -> LN2 -> GELU MLP + res
// Big GEMMs (qkv/fc1/fc2): 256x256 8-phase pipelined template (T2 swizzle,
// T3/T4 counted vmcnt, T5 setprio), BK=64, 512 threads, 128 KiB dynamic LDS.
// proj: 128x128 m97-style core. Attention: fused scores+softmax+PV.

typedef _Float16 f16;
typedef _Float16 f16x4 __attribute__((ext_vector_type(4)));
typedef _Float16 f16x8 __attribute__((ext_vector_type(8)));
typedef float f32x4 __attribute__((ext_vector_type(4)));

#define DEV static __device__ __forceinline__

DEV void gload16(const void* g, void* l) {
  __builtin_amdgcn_global_load_lds(
      (__attribute__((address_space(1))) void*)(uintptr_t)g,
      (__attribute__((address_space(3))) void*)(uintptr_t)l, 16, 0, 0);
}

DEV f32x4 mfma16(f16x8 a, f16x8 b, f32x4 c) {
  return __builtin_amdgcn_mfma_f32_16x16x32_f16(a, b, c, 0, 0, 0);
}

// ===================== 256x256 8-phase GEMM core ==========================
// C[256,256] tile = A[256,K] * B[256,K]^T. 8 waves; phase q=(a,b) computes
// 128x128 quadrant (a,b) over K=64; wave slice: rows a*128+(w>>2)*64, cols
// b*128+(w&3)*32. LDS: 2 buf x 4 slots (Ah0,Ah1,Bh0,Bh1) x 128x64 f16.
// Swizzle: elem (r,c) of a slot at r*64 + (((c>>3)^(r&7))<<3) + (c&7).

DEV f16* slotp(f16* L, int buf, int s) { return L + buf * 32768 + s * 8192; }

DEV void stg(const f16* base, int koff, f16* sl, int tid, size_t ld) {
  gload16(base + koff, sl + tid * 8);
  gload16(base + koff + ld * 64, sl + 4096 + tid * 8);
}

template<int VM, bool ST>
DEV void do_phase(const f16* Aslot, const f16* Bslot, int base_ar, int base_br,
                  int ch0, int ch1, f32x4 (&acc)[4][2],
                  const f16* gsrc, size_t gstep, f16* sl, int tid)
{
  f16x8 af[4][2], bf[2][2];
#pragma unroll
  for (int fi = 0; fi < 4; ++fi) {
    af[fi][0] = *(const f16x8*)(Aslot + base_ar + fi * 1024 + ch0);
    af[fi][1] = *(const f16x8*)(Aslot + base_ar + fi * 1024 + ch1);
  }
#pragma unroll
  for (int fj = 0; fj < 2; ++fj) {
    bf[fj][0] = *(const f16x8*)(Bslot + base_br + fj * 1024 + ch0);
    bf[fj][1] = *(const f16x8*)(Bslot + base_br + fj * 1024 + ch1);
  }
  if (ST) {
    gload16(gsrc, sl + tid * 8);
    gload16(gsrc + gstep, sl + 4096 + tid * 8);
  }
  __builtin_amdgcn_s_barrier();
  asm volatile("s_waitcnt lgkmcnt(0)" ::: "memory");
  __builtin_amdgcn_sched_barrier(0);
  __builtin_amdgcn_s_setprio(1);
#pragma unroll
  for (int fi = 0; fi < 4; ++fi)
#pragma unroll
    for (int fj = 0; fj < 2; ++fj) {
      acc[fi][fj] = mfma16(af[fi][0], bf[fj][0], acc[fi][fj]);
      acc[fi][fj] = mfma16(af[fi][1], bf[fj][1], acc[fi][fj]);
    }
  __builtin_amdgcn_s_setprio(0);
  if (VM == 4) asm volatile("s_waitcnt vmcnt(4)" ::: "memory");
  if (VM == 0) asm volatile("s_waitcnt vmcnt(0)" ::: "memory");
  __builtin_amdgcn_s_barrier();
}

DEV void gemm8_core(const f16* __restrict__ A, const f16* __restrict__ B,
                    size_t lda, size_t ldb, int NT, int bm, int bn,
                    f16* L, int tid, f32x4 (&acc)[4][4][2])
{
  const int lane = tid & 63, w = tid >> 6;
  const int lr = lane & 15, lg = lane >> 4;
  const int rl = tid >> 3;
  const int gc = ((tid & 7) ^ (rl & 7)) << 3;   // pre-swizzled src col (elems)
  const f16* a0 = A + (size_t)(bm * 256 + rl) * lda + gc;
  const f16* a1 = a0 + (size_t)128 * lda;
  const f16* b0 = B + (size_t)(bn * 256 + rl) * ldb + gc;
  const f16* b1 = b0 + (size_t)128 * ldb;
  const size_t sa = lda * 64, sb = ldb * 64;

  const int base_ar = ((w >> 2) * 64 + lr) * 64;
  const int base_br = ((w & 3) * 32 + lr) * 64;
  const int sx = lr & 7;
  const int ch0 = ((0 + lg) ^ sx) << 3;
  const int ch1 = ((4 + lg) ^ sx) << 3;

  // prologue: tile0 all 4 halves + tile1 Ah0,Bh0  (order matters for vmcnt)
  stg(a0, 0, slotp(L, 0, 0), tid, lda);
  stg(b0, 0, slotp(L, 0, 2), tid, ldb);
  stg(b1, 0, slotp(L, 0, 3), tid, ldb);
  stg(a1, 0, slotp(L, 0, 1), tid, lda);
  stg(a0, 64, slotp(L, 1, 0), tid, lda);
  stg(b0, 64, slotp(L, 1, 2), tid, ldb);
  asm volatile("s_waitcnt vmcnt(4)" ::: "memory");
  __builtin_amdgcn_s_barrier();

  int u = 0;
  for (; u < NT - 2; ++u) {
    const int cb = u & 1, nb = cb ^ 1;
    const f16* As0 = slotp(L, cb, 0);
    const f16* As1 = slotp(L, cb, 1);
    const f16* Bs0 = slotp(L, cb, 2);
    const f16* Bs1 = slotp(L, cb, 3);
    const int k1 = (u + 1) * 64, k2 = (u + 2) * 64;
    do_phase<-1, true>(As0, Bs0, base_ar, base_br, ch0, ch1, acc[0], b1 + k1, sb, slotp(L, nb, 3), tid);
    do_phase<-1, true>(As0, Bs1, base_ar, base_br, ch0, ch1, acc[1], a1 + k1, sa, slotp(L, nb, 1), tid);
    do_phase<-1, true>(As1, Bs0, base_ar, base_br, ch0, ch1, acc[2], a0 + k2, sa, slotp(L, cb, 0), tid);
    do_phase< 4, true>(As1, Bs1, base_ar, base_br, ch0, ch1, acc[3], b0 + k2, sb, slotp(L, cb, 2), tid);
  }
  { // u = NT-2: stage only tile NT-1's Bh1/Ah1; drain at boundary
    const int cb = u & 1, nb = cb ^ 1;
    const f16* As0 = slotp(L, cb, 0);
    const f16* As1 = slotp(L, cb, 1);
    const f16* Bs0 = slotp(L, cb, 2);
    const f16* Bs1 = slotp(L, cb, 3);
    const int k1 = (u + 1) * 64;
    do_phase<-1, true >(As0, Bs0, base_ar, base_br, ch0, ch1, acc[0], b1 + k1, sb, slotp(L, nb, 3), tid);
    do_phase<-1, true >(As0, Bs1, base_ar, base_br, ch0, ch1, acc[1], a1 + k1, sa, slotp(L, nb, 1), tid);
    do_phase<-1, false>(As1, Bs0, base_ar, base_br, ch0, ch1, acc[2], nullptr, 0, nullptr, tid);
    do_phase< 0, false>(As1, Bs1, base_ar, base_br, ch0, ch1, acc[3], nullptr, 0, nullptr, tid);
    ++u;
  }
  { // u = NT-1: compute only
    const int cb = u & 1;
    const f16* As0 = slotp(L, cb, 0);
    const f16* As1 = slotp(L, cb, 1);
    const f16* Bs0 = slotp(L, cb, 2);
    const f16* Bs1 = slotp(L, cb, 3);
    do_phase<-1, false>(As0, Bs0, base_ar, base_br, ch0, ch1, acc[0], nullptr, 0, nullptr, tid);
    do_phase<-1, false>(As0, Bs1, base_ar, base_br, ch0, ch1, acc[1], nullptr, 0, nullptr, tid);
    do_phase<-1, false>(As1, Bs0, base_ar, base_br, ch0, ch1, acc[2], nullptr, 0, nullptr, tid);
    do_phase<-1, false>(As1, Bs1, base_ar, base_br, ch0, ch1, acc[3], nullptr, 0, nullptr, tid);
  }
}

DEV void xcd_decomp(int& bm, int& bn) {
  const int id = blockIdx.x, nwg = gridDim.x;
  const int cpx = nwg >> 3;                       // all grids % 8 == 0
  const int id2 = (id & 7) * cpx + (id >> 3);
  bm = id2 & 31;                                   // gm = 32 (M = 8192)
  bn = id2 >> 5;
}

// ---------------- qkv: xn[8192,1024] @ wqkv[3072,1024]^T, scatter q/k/vT ----
__global__ __launch_bounds__(512) void k_qkv8(const f16* __restrict__ xn,
                                              const f16* __restrict__ wq,
                                              f16* __restrict__ qb,
                                              f16* __restrict__ kb,
                                              f16* __restrict__ vT)
{
  extern __shared__ __align__(16) f16 L[];
  int bm, bn; xcd_decomp(bm, bn);
  const int tid = threadIdx.x, lane = tid & 63, w = tid >> 6;
  const int lr = lane & 15, lg = lane >> 4;
  f32x4 acc[4][4][2] = {};
  gemm8_core(xn, wq, 1024, 1024, 16, bm, bn, L, tid, acc);
  const int secq = bn >> 2;
  const int r00 = bm * 256 + ((w >> 2) << 6) + (lg << 2);
  const int c00 = ((bn & 3) << 8) + ((w & 3) << 5) + lr;
#pragma unroll
  for (int a = 0; a < 2; ++a)
#pragma unroll
    for (int b = 0; b < 2; ++b)
#pragma unroll
      for (int fi = 0; fi < 4; ++fi)
#pragma unroll
        for (int fj = 0; fj < 2; ++fj)
#pragma unroll
          for (int e = 0; e < 4; ++e) {
            const int r = r00 + a * 128 + fi * 16 + e;
            const int cq = c00 + b * 128 + fj * 16;
            const int h = cq >> 6, d = cq & 63;
            const int bb = r >> 10, n = r & 1023;
            const int bh = (bb << 4) + h;
            const f16 val = (f16)acc[a * 2 + b][fi][fj][e];
            if (secq == 0)      qb[((size_t)bh * 1024 + n) * 64 + d] = val;
            else if (secq == 1) kb[((size_t)bh * 1024 + n) * 64 + d] = val;
            else                vT[((size_t)bh * 64 + d) * 1024 + n] = val;
          }
}

// ---------------- fc1: h = gelu(xn2 @ wfc1^T + bfc1) ----------------
__global__ __launch_bounds__(512) void k_fc18(const f16* __restrict__ xn,
                                              const f16* __restrict__ wf,
                                              const float* __restrict__ bfc1,
                                              f16* __restrict__ hb)
{
  extern __shared__ __align__(16) f16 L[];
  int bm, bn; xcd_decomp(bm, bn);
  const int tid = threadIdx.x, lane = tid & 63, w = tid >> 6;
  const int lr = lane & 15, lg = lane >> 4;
  f32x4 acc[4][4][2] = {};
  gemm8_core(xn, wf, 1024, 1024, 16, bm, bn, L, tid, acc);
  const int r00 = bm * 256 + ((w >> 2) << 6) + (lg << 2);
  const int c00 = bn * 256 + ((w & 3) << 5) + lr;
#pragma unroll
  for (int a = 0; a < 2; ++a)
#pragma unroll
    for (int b = 0; b < 2; ++b)
#pragma unroll
      for (int fj = 0; fj < 2; ++fj) {
        const int c = c00 + b * 128 + fj * 16;
        const float bias = bfc1[c];
#pragma unroll
        for (int fi = 0; fi < 4; ++fi)
#pragma unroll
          for (int e = 0; e < 4; ++e) {
            const int r = r00 + a * 128 + fi * 16 + e;
            const float t = acc[a * 2 + b][fi][fj][e] + bias;
            const float ge = 0.5f * t * (1.0f + erff(t * 0.70710678118654752f));
            hb[(size_t)r * 4096 + c] = (f16)ge;
          }
      }
}

// ---------------- fc2: out = h @ wfc2^T + bfc2 + xmid ----------------
__global__ __launch_bounds__(512) void k_fc28(const f16* __restrict__ hb,
                                              const f16* __restrict__ wf,
                                              const float* __restrict__ bfc2,
                                              const float* __restrict__ xmid,
                                              float* __restrict__ out)
{
  extern __shared__ __align__(16) f16 L[];
  int bm, bn; xcd_decomp(bm, bn);
  const int tid = threadIdx.x, lane = tid & 63, w = tid >> 6;
  const int lr = lane & 15, lg = lane >> 4;
  f32x4 acc[4][4][2] = {};
  gemm8_core(hb, wf, 4096, 4096, 64, bm, bn, L, tid, acc);
  const int r00 = bm * 256 + ((w >> 2) << 6) + (lg << 2);
  const int c00 = bn * 256 + ((w & 3) << 5) + lr;
#pragma unroll
  for (int a = 0; a < 2; ++a)
#pragma unroll
    for (int b = 0; b < 2; ++b)
#pragma unroll
      for (int fj = 0; fj < 2; ++fj) {
        const int c = c00 + b * 128 + fj * 16;
        const float bias = bfc2[c];
#pragma unroll
        for (int fi = 0; fi < 4; ++fi)
#pragma unroll
          for (int e = 0; e < 4; ++e) {
            const int r = r00 + a * 128 + fi * 16 + e;
            const size_t idx = (size_t)r * 1024 + c;
            out[idx] = acc[a * 2 + b][fi][fj][e] + bias + xmid[idx];
          }
      }
}

// ===================== 128x128 m97-style core (proj) ======================
DEV void nt_core(const f16* __restrict__ A, const f16* __restrict__ B,
                 int lda, int ldb, int K, f16* As, f16* Bs, f32x4 acc[4][4])
{
  const int tid  = threadIdx.x;
  const int lane = tid & 63;
  const int w    = tid >> 6;
  const int wm   = (w >> 1) << 6;
  const int wn   = (w & 1) << 6;
  const int srow = tid >> 2;
  const int scs  = (((tid & 3) ^ ((srow >> 1) & 3)) << 3);
  const size_t aoff0 = (size_t)srow * lda + scs;
  const size_t aoff1 = (size_t)(srow + 64) * lda + scs;
  const size_t boff0 = (size_t)srow * ldb + scs;
  const size_t boff1 = (size_t)(srow + 64) * ldb + scs;
  f16* la0 = As + tid * 8;
  f16* la1 = As + 2048 + tid * 8;
  f16* lb0 = Bs + tid * 8;
  f16* lb1 = Bs + 2048 + tid * 8;
  const int frow = lane & 15;
  const int fcs  = (((lane >> 4) ^ ((frow >> 1) & 3)) << 3);

  for (int k0 = 0; k0 < K; k0 += 32) {
    gload16(A + aoff0 + k0, la0);
    gload16(A + aoff1 + k0, la1);
    gload16(B + boff0 + k0, lb0);
    gload16(B + boff1 + k0, lb1);
    __syncthreads();
    f16x8 af[4], bf[4];
#pragma unroll
    for (int i = 0; i < 4; ++i) {
      af[i] = *(const f16x8*)(As + (wm + i * 16 + frow) * 32 + fcs);
      bf[i] = *(const f16x8*)(Bs + (wn + i * 16 + frow) * 32 + fcs);
    }
#pragma unroll
    for (int i = 0; i < 4; ++i)
#pragma unroll
      for (int j = 0; j < 4; ++j)
        acc[i][j] = mfma16(af[i], bf[j], acc[i][j]);
    __syncthreads();
  }
}

// ---------------- fp32 -> fp16 convert ----------------
__global__ __launch_bounds__(256) void k_cvt(const float* __restrict__ in,
                                             f16* __restrict__ out, int n4)
{
  int i = blockIdx.x * blockDim.x + threadIdx.x;
  if (i >= n4) return;
  float4 f = ((const float4*)in)[i];
  f16x4 o; o[0] = (f16)f.x; o[1] = (f16)f.y; o[2] = (f16)f.z; o[3] = (f16)f.w;
  ((f16x4*)out)[i] = o;
}

// ---------------- LayerNorm (1024 cols, 1 row/block) ----------------
__global__ __launch_bounds__(256) void k_ln(const float* __restrict__ xin,
                                            const float* __restrict__ g,
                                            const float* __restrict__ bb,
                                            f16* __restrict__ out)
{
  __shared__ float red[8];
  const int tid = threadIdx.x;
  const size_t row = blockIdx.x;
  const float4 v = ((const float4*)(xin + row * 1024))[tid];
  float s  = v.x + v.y + v.z + v.w;
  float sq = v.x * v.x + v.y * v.y + v.z * v.z + v.w * v.w;
#pragma unroll
  for (int off = 32; off > 0; off >>= 1) { s += __shfl_xor(s, off); sq += __shfl_xor(sq, off); }
  if ((tid & 63) == 0) { red[tid >> 6] = s; red[4 + (tid >> 6)] = sq; }
  __syncthreads();
  s  = red[0] + red[1] + red[2] + red[3];
  sq = red[4] + red[5] + red[6] + red[7];
  const float mu = s * (1.0f / 1024.0f);
  const float rs = rsqrtf(sq * (1.0f / 1024.0f) - mu * mu + 1e-5f);
  const float4 gg = ((const float4*)g)[tid];
  const float4 bv = ((const float4*)bb)[tid];
  f16x4 o;
  o[0] = (f16)((v.x - mu) * rs * gg.x + bv.x);
  o[1] = (f16)((v.y - mu) * rs * gg.y + bv.y);
  o[2] = (f16)((v.z - mu) * rs * gg.z + bv.z);
  o[3] = (f16)((v.w - mu) * rs * gg.w + bv.w);
  ((f16x4*)(out + row * 1024))[tid] = o;
}

// ---------------- fused attention ----------------
__global__ __launch_bounds__(256) void k_attn(const f16* __restrict__ qb,
                                              const f16* __restrict__ kb,
                                              const f16* __restrict__ vT,
                                              float* __restrict__ attn,
                                              f16* __restrict__ y2)
{
  __shared__ __align__(16) f16 P[32 * 1024];   // exactly 64 KB
  const int tid = threadIdx.x, lane = tid & 63, w = tid >> 6;
  const int lr = lane & 15, lg = lane >> 4;
  const int bh = blockIdx.y;
  const int m0 = blockIdx.x * 32;
  const f16* Qb = qb + ((size_t)bh << 16);
  const f16* Kb = kb + ((size_t)bh << 16);
  const f16* Vt = vT + ((size_t)bh << 16);

  f16x8 qf[2][2];
#pragma unroll
  for (int i = 0; i < 2; ++i)
#pragma unroll
    for (int ks = 0; ks < 2; ++ks)
      qf[i][ks] = *(const f16x8*)(Qb + (size_t)(m0 + i * 16 + lr) * 64 + ks * 32 + lg * 8);

  for (int cc = 0; cc < 4; ++cc) {
    const int cb = (w << 8) + (cc << 6);
    f16x8 bf[4][2];
#pragma unroll
    for (int j = 0; j < 4; ++j)
#pragma unroll
      for (int ks = 0; ks < 2; ++ks)
        bf[j][ks] = *(const f16x8*)(Kb + (size_t)(cb + j * 16 + lr) * 64 + ks * 32 + lg * 8);
    f32x4 acc[2][4] = {};
#pragma unroll
    for (int i = 0; i < 2; ++i)
#pragma unroll
      for (int j = 0; j < 4; ++j) {
        acc[i][j] = mfma16(qf[i][0], bf[j][0], acc[i][j]);
        acc[i][j] = mfma16(qf[i][1], bf[j][1], acc[i][j]);
      }
#pragma unroll
    for (int i = 0; i < 2; ++i)
#pragma unroll
      for (int j = 0; j < 4; ++j)
#pragma unroll
        for (int e = 0; e < 4; ++e) {
          const int r = i * 16 + (lg << 2) + e;
          const int c = cb + j * 16 + lr;
          P[(r << 10) + (((c >> 3) ^ (r & 7)) << 3) + (c & 7)] = (f16)(acc[i][j][e] * 0.125f);
        }
  }
  __syncthreads();

  const int r2 = tid >> 3;
  f16* Prow = P + (r2 << 10);
  const int rx = r2 & 7;
  float mrow = -1e30f;
#pragma unroll
  for (int q = 0; q < 16; ++q) {
    const int c = (tid & 7) + (q << 3);
    f16x8 v = *(const f16x8*)(Prow + ((c ^ rx) << 3));
#pragma unroll
    for (int e = 0; e < 8; ++e) mrow = fmaxf(mrow, (float)v[e]);
  }
  mrow = fmaxf(mrow, __shfl_xor(mrow, 1));
  mrow = fmaxf(mrow, __shfl_xor(mrow, 2));
  mrow = fmaxf(mrow, __shfl_xor(mrow, 4));
  float ssum = 0.f;
#pragma unroll
  for (int q = 0; q < 16; ++q) {
    const int c = (tid & 7) + (q << 3);
    f16x8 v = *(const f16x8*)(Prow + ((c ^ rx) << 3));
    f16x8 o;
#pragma unroll
    for (int e = 0; e < 8; ++e) {
      const float ev = __expf((float)v[e] - mrow);
      ssum += ev;
      o[e] = (f16)ev;
    }
    *(f16x8*)(Prow + ((c ^ rx) << 3)) = o;
  }
  ssum += __shfl_xor(ssum, 1);
  ssum += __shfl_xor(ssum, 2);
  ssum += __shfl_xor(ssum, 4);
  const float inv = 1.0f / ssum;
  float* Aout = attn + ((size_t)bh << 20) + ((size_t)(m0 + r2) << 10);
#pragma unroll
  for (int q = 0; q < 16; ++q) {
    const int c = (tid & 7) + (q << 3);
    f16x8 v = *(const f16x8*)(Prow + ((c ^ rx) << 3));
    f16x8 nv;
    float4 o0, o1;
    o0.x = (float)v[0] * inv; o0.y = (float)v[1] * inv;
    o0.z = (float)v[2] * inv; o0.w = (float)v[3] * inv;
    o1.x = (float)v[4] * inv; o1.y = (float)v[5] * inv;
    o1.z = (float)v[6] * inv; o1.w = (float)v[7] * inv;
#pragma unroll
    for (int e = 0; e < 8; ++e) nv[e] = (f16)((float)v[e] * inv);
    ((float4*)(Aout + (c << 3)))[0] = o0;
    ((float4*)(Aout + (c << 3)))[1] = o1;
    *(f16x8*)(Prow + ((c ^ rx) << 3)) = nv;
  }
  __syncthreads();

  const int dc = w << 4;
  f32x4 acc2[2] = {};
#pragma unroll 4
  for (int k0 = 0; k0 < 1024; k0 += 32) {
    const f16x8 bf = *(const f16x8*)(Vt + (size_t)(dc + lr) * 1024 + k0 + lg * 8);
#pragma unroll
    for (int i = 0; i < 2; ++i) {
      const int ra = i * 16 + lr;
      const int ch = (k0 >> 3) + lg;
      const f16x8 af = *(const f16x8*)(P + (ra << 10) + ((ch ^ (ra & 7)) << 3));
      acc2[i] = mfma16(af, bf, acc2[i]);
    }
  }
  const int b = bh >> 4, h = bh & 15;
#pragma unroll
  for (int i = 0; i < 2; ++i)
#pragma unroll
    for (int e = 0; e < 4; ++e) {
      const int rloc = i * 16 + (lg << 2) + e;
      y2[(size_t)(b * 1024 + m0 + rloc) * 1024 + (h << 6) + dc + lr] = (f16)acc2[i][e];
    }
}

// ---------------- proj: xmid = y2 @ wproj^T + bproj + x ----------------
__global__ __launch_bounds__(256) void k_proj(const f16* __restrict__ y2,
                                              const f16* __restrict__ wp,
                                              const float* __restrict__ bproj,
                                              const float* __restrict__ x,
                                              float* __restrict__ xmid)
{
  __shared__ __align__(16) f16 As[4096], Bs[4096];
  f32x4 acc[4][4] = {};
  nt_core(y2 + (size_t)blockIdx.x * 128 * 1024, wp + (size_t)blockIdx.y * 128 * 1024,
          1024, 1024, 1024, As, Bs, acc);
  const int tid = threadIdx.x, lane = tid & 63, w = tid >> 6;
  const int r0 = blockIdx.x * 128 + ((w >> 1) << 6) + ((lane >> 4) << 2);
  const int c0 = blockIdx.y * 128 + ((w & 1) << 6) + (lane & 15);
#pragma unroll
  for (int i = 0; i < 4; ++i)
#pragma unroll
    for (int j = 0; j < 4; ++j) {
      const int c = c0 + j * 16;
      const float bias = bproj[c];
#pragma unroll
      for (int e = 0; e < 4; ++e) {
        const size_t idx = (size_t)(r0 + i * 16 + e) * 1024 + c;
        xmid[idx] = acc[i][j][e] + bias + x[idx];
      }
    }
}

extern "C" void kernel_launch(void* const* d_in, const int* in_sizes, int n_in,
                              void* d_out, int out_size, void* d_ws, size_t ws_size,
                              hipStream_t stream)
{
  const float* x     = (const float*)d_in[0];
  const float* ln1g  = (const float*)d_in[1];
  const float* ln1b  = (const float*)d_in[2];
  const float* wqkv  = (const float*)d_in[3];
  const float* wproj = (const float*)d_in[4];
  const float* bproj = (const float*)d_in[5];
  const float* ln2g  = (const float*)d_in[6];
  const float* ln2b  = (const float*)d_in[7];
  const float* wfc1  = (const float*)d_in[8];
  const float* bfc1  = (const float*)d_in[9];
  const float* wfc2  = (const float*)d_in[10];
  const float* bfc2  = (const float*)d_in[11];

  char* ws = (char*)d_ws;
  f16* wqkv_h  = (f16*)(ws);                    //  6 MB
  f16* wproj_h = (f16*)(ws + 6291456);          //  2 MB
  f16* wfc1_h  = (f16*)(ws + 8388608);          //  8 MB
  f16* wfc2_h  = (f16*)(ws + 16777216);         //  8 MB
  f16* xn      = (f16*)(ws + 25165824);         // 16 MB (xn1, reused as xn2)
  f16* qb      = (f16*)(ws + 41943040);         // 16 MB
  f16* kb      = (f16*)(ws + 58720256);         // 16 MB
  f16* vT      = (f16*)(ws + 75497472);         // 16 MB
  f16* y2      = (f16*)(ws + 92274688);         // 16 MB
  float* xmid  = (float*)(ws + 109051904);      // 32 MB
  f16* hb      = (f16*)(ws + 41943040);         // 64 MB, aliases qb..y2 (dead by fc1)

  float* out_x = (float*)d_out;
  float* attn  = (float*)d_out + 8388608;

  // allow 128 KiB dynamic LDS on the 8-phase kernels (idempotent, not a stream op)
  hipFuncSetAttribute((const void*)k_qkv8, hipFuncAttributeMaxDynamicSharedMemorySize, 131072);
  hipFuncSetAttribute((const void*)k_fc18, hipFuncAttributeMaxDynamicSharedMemorySize, 131072);
  hipFuncSetAttribute((const void*)k_fc28, hipFuncAttributeMaxDynamicSharedMemorySize, 131072);

  k_cvt<<<3072, 256, 0, stream>>>(wqkv,  wqkv_h,  786432);
  k_cvt<<<1024, 256, 0, stream>>>(wproj, wproj_h, 262144);
  k_cvt<<<4096, 256, 0, stream>>>(wfc1,  wfc1_h,  1048576);
  k_cvt<<<4096, 256, 0, stream>>>(wfc2,  wfc2_h,  1048576);

  k_ln<<<8192, 256, 0, stream>>>(x, ln1g, ln1b, xn);
  k_qkv8<<<384, 512, 131072, stream>>>(xn, wqkv_h, qb, kb, vT);
  k_attn<<<dim3(32, 128), 256, 0, stream>>>(qb, kb, vT, attn, y2);
  k_proj<<<dim3(64, 8), 256, 0, stream>>>(y2, wproj_h, bproj, x, xmid);
  k_ln<<<8192, 256, 0, stream>>>(xmid, ln2g, ln2b, xn);
  k_fc18<<<512, 512, 131072, stream>>>(xn, wfc1_h, bfc1, hb);
  k_fc28<<<128, 512, 131072, stream>>>(hb, wfc2_h, bfc2, xmid, out_x);
}

// Round 5
// 524.040 us; speedup vs baseline: 1.6266x; 1.6266x over previous
//
#include <hip/hip_runtime.h>
#include <cstdint>
#include <math.h>

// Transformer block: LN1 -> QKV -> fused MHA (attn probs = output[1]) -> proj+res
//                    -> LN2 -> GELU MLP + res -> output[0]
// GEMMs: fp16 MFMA 16x16x32, 128x128 tiles, BK=64 (half the barrier drains of
// BK=32), global_load_lds width-16 staging, XOR chunk swizzle realized via
// pre-swizzled global source (write) + swizzled ds_read (read).

typedef _Float16 f16;
typedef _Float16 f16x4 __attribute__((ext_vector_type(4)));
typedef _Float16 f16x8 __attribute__((ext_vector_type(8)));
typedef float f32x4 __attribute__((ext_vector_type(4)));

#define DEV static __device__ __forceinline__

DEV void gload16(const void* g, void* l) {
  __builtin_amdgcn_global_load_lds(
      (__attribute__((address_space(1))) void*)(uintptr_t)g,
      (__attribute__((address_space(3))) void*)(uintptr_t)l, 16, 0, 0);
}

DEV f32x4 mfma16(f16x8 a, f16x8 b, f32x4 c) {
  return __builtin_amdgcn_mfma_f32_16x16x32_f16(a, b, c, 0, 0, 0);
}

// ===== 128x128 NT GEMM core, BK=64: C_tile = A[128,K] * B[128,K]^T =========
// LDS As/Bs: 128 rows x 64 cols f16 (16 KB each). Row = 8 chunks of 8 f16.
// Swizzle: lds chunk cl at row r holds global chunk cl ^ (r & 7).
// Staging: wave w, load L covers rows w*32+L*8+(lane>>3), src col chunk
// (lane&7)^((lane>>3)&7); dest linear -> involution consistent with read.
DEV void nt_core64(const f16* __restrict__ A, const f16* __restrict__ B,
                   size_t lda, size_t ldb, int K, f16* As, f16* Bs,
                   f32x4 acc[4][4])
{
  const int tid  = threadIdx.x;
  const int lane = tid & 63;
  const int w    = tid >> 6;
  const int wm   = (w >> 1) << 6;
  const int wn   = (w & 1) << 6;
  const int frow = lane & 15;
  const int lg   = lane >> 4;

  const int srow0 = w * 32 + (lane >> 3);
  const int scol  = ((lane & 7) ^ ((lane >> 3) & 7)) << 3;
  const f16* Ab = A + (size_t)srow0 * lda + scol;
  const f16* Bb = B + (size_t)srow0 * ldb + scol;
  f16* la = As + w * 2048 + lane * 8;   // + L*512
  f16* lb = Bs + w * 2048 + lane * 8;

  for (int k0 = 0; k0 < K; k0 += 64) {
#pragma unroll
    for (int L = 0; L < 4; ++L)
      gload16(Ab + (size_t)(L * 8) * lda + k0, la + L * 512);
#pragma unroll
    for (int L = 0; L < 4; ++L)
      gload16(Bb + (size_t)(L * 8) * ldb + k0, lb + L * 512);
    __syncthreads();
#pragma unroll
    for (int kc = 0; kc < 2; ++kc) {
      f16x8 af[4], bf[4];
#pragma unroll
      for (int i = 0; i < 4; ++i) {
        const int ra = wm + i * 16 + frow;
        const int rb = wn + i * 16 + frow;
        af[i] = *(const f16x8*)(As + ra * 64 + ((((kc << 2) + lg) ^ (ra & 7)) << 3));
        bf[i] = *(const f16x8*)(Bs + rb * 64 + ((((kc << 2) + lg) ^ (rb & 7)) << 3));
      }
#pragma unroll
      for (int i = 0; i < 4; ++i)
#pragma unroll
        for (int j = 0; j < 4; ++j)
          acc[i][j] = mfma16(af[i], bf[j], acc[i][j]);
    }
    __syncthreads();
  }
}

// ---------------- fused fp32 -> fp16 convert (all 4 weight arrays) ----------
// dests are contiguous in ws: one f16[12582912] stream.
__global__ __launch_bounds__(256) void k_cvtall(const float* __restrict__ s0,
                                                const float* __restrict__ s1,
                                                const float* __restrict__ s2,
                                                const float* __restrict__ s3,
                                                f16* __restrict__ out)
{
  const int i = blockIdx.x * blockDim.x + threadIdx.x;   // float4 index
  const float* src;
  int off;
  if (i < 786432)       { src = s0; off = 0; }
  else if (i < 1048576) { src = s1; off = 786432; }
  else if (i < 2097152) { src = s2; off = 1048576; }
  else                  { src = s3; off = 2097152; }
  const float4 f = ((const float4*)src)[i - off];
  f16x4 o; o[0] = (f16)f.x; o[1] = (f16)f.y; o[2] = (f16)f.z; o[3] = (f16)f.w;
  ((f16x4*)out)[i] = o;
}

// ---------------- LayerNorm (1024 cols, 1 row/block) ----------------
__global__ __launch_bounds__(256) void k_ln(const float* __restrict__ xin,
                                            const float* __restrict__ g,
                                            const float* __restrict__ bb,
                                            f16* __restrict__ out)
{
  __shared__ float red[8];
  const int tid = threadIdx.x;
  const size_t row = blockIdx.x;
  const float4 v = ((const float4*)(xin + row * 1024))[tid];
  float s  = v.x + v.y + v.z + v.w;
  float sq = v.x * v.x + v.y * v.y + v.z * v.z + v.w * v.w;
#pragma unroll
  for (int off = 32; off > 0; off >>= 1) { s += __shfl_xor(s, off); sq += __shfl_xor(sq, off); }
  if ((tid & 63) == 0) { red[tid >> 6] = s; red[4 + (tid >> 6)] = sq; }
  __syncthreads();
  s  = red[0] + red[1] + red[2] + red[3];
  sq = red[4] + red[5] + red[6] + red[7];
  const float mu = s * (1.0f / 1024.0f);
  const float rs = rsqrtf(sq * (1.0f / 1024.0f) - mu * mu + 1e-5f);
  const float4 gg = ((const float4*)g)[tid];
  const float4 bv = ((const float4*)bb)[tid];
  f16x4 o;
  o[0] = (f16)((v.x - mu) * rs * gg.x + bv.x);
  o[1] = (f16)((v.y - mu) * rs * gg.y + bv.y);
  o[2] = (f16)((v.z - mu) * rs * gg.z + bv.z);
  o[3] = (f16)((v.w - mu) * rs * gg.w + bv.w);
  ((f16x4*)(out + row * 1024))[tid] = o;
}

// ---------------- QKV GEMM: [8192,1024] x [3072,1024]^T ----------------
__global__ __launch_bounds__(256) void k_qkv(const f16* __restrict__ xn,
                                             const f16* __restrict__ wq,
                                             f16* __restrict__ qb, f16* __restrict__ kb,
                                             f16* __restrict__ vT)
{
  __shared__ __align__(16) f16 As[8192], Bs[8192];
  f32x4 acc[4][4] = {};
  const int bm = blockIdx.x, bn = blockIdx.y;
  nt_core64(xn + (size_t)bm * 128 * 1024, wq + (size_t)bn * 128 * 1024,
            1024, 1024, 1024, As, Bs, acc);
  const int tid = threadIdx.x, lane = tid & 63, w = tid >> 6;
  const int r0 = bm * 128 + ((w >> 1) << 6) + ((lane >> 4) << 2);
  const int c0 = bn * 128 + ((w & 1) << 6);
  const int sec = (bn * 128) >> 10;
#pragma unroll
  for (int i = 0; i < 4; ++i) {
#pragma unroll
    for (int j = 0; j < 4; ++j) {
      const int o = c0 + j * 16 + (lane & 15);
      const int h = (o & 1023) >> 6, d = o & 63;
#pragma unroll
      for (int e = 0; e < 4; ++e) {
        const int m = r0 + i * 16 + e;
        const int b = m >> 10, n = m & 1023;
        const int bh = (b << 4) + h;
        const f16 val = (f16)acc[i][j][e];
        if (sec == 0)      qb[((size_t)bh * 1024 + n) * 64 + d] = val;
        else if (sec == 1) kb[((size_t)bh * 1024 + n) * 64 + d] = val;
        else               vT[((size_t)bh * 64 + d) * 1024 + n] = val;
      }
    }
  }
}

// ---------------- fused attention: S=QK^T*scale, softmax, attn out, y=PV ------
// LDS P[32][1024] fp16, chunk-swizzled: (r,c) at r*1024 + (((c>>3)^(r&7))<<3)+(c&7)
__global__ __launch_bounds__(256) void k_attn(const f16* __restrict__ qb,
                                              const f16* __restrict__ kb,
                                              const f16* __restrict__ vT,
                                              float* __restrict__ attn,
                                              f16* __restrict__ y2)
{
  __shared__ __align__(16) f16 P[32 * 1024];   // exactly 64 KB
  const int tid = threadIdx.x, lane = tid & 63, w = tid >> 6;
  const int lr = lane & 15, lg = lane >> 4;
  const int bh = blockIdx.y;
  const int m0 = blockIdx.x * 32;
  const f16* Qb = qb + ((size_t)bh << 16);
  const f16* Kb = kb + ((size_t)bh << 16);
  const f16* Vt = vT + ((size_t)bh << 16);

  f16x8 qf[2][2];
#pragma unroll
  for (int i = 0; i < 2; ++i)
#pragma unroll
    for (int ks = 0; ks < 2; ++ks)
      qf[i][ks] = *(const f16x8*)(Qb + (size_t)(m0 + i * 16 + lr) * 64 + ks * 32 + lg * 8);

  // phase 1: S -> P_lds (fp16, scaled)
  for (int cc = 0; cc < 4; ++cc) {
    const int cb = (w << 8) + (cc << 6);
    f16x8 bf[4][2];
#pragma unroll
    for (int j = 0; j < 4; ++j)
#pragma unroll
      for (int ks = 0; ks < 2; ++ks)
        bf[j][ks] = *(const f16x8*)(Kb + (size_t)(cb + j * 16 + lr) * 64 + ks * 32 + lg * 8);
    f32x4 acc[2][4] = {};
#pragma unroll
    for (int i = 0; i < 2; ++i)
#pragma unroll
      for (int j = 0; j < 4; ++j) {
        acc[i][j] = mfma16(qf[i][0], bf[j][0], acc[i][j]);
        acc[i][j] = mfma16(qf[i][1], bf[j][1], acc[i][j]);
      }
#pragma unroll
    for (int i = 0; i < 2; ++i)
#pragma unroll
      for (int j = 0; j < 4; ++j)
#pragma unroll
        for (int e = 0; e < 4; ++e) {
          const int r = i * 16 + (lg << 2) + e;
          const int c = cb + j * 16 + lr;
          P[(r << 10) + (((c >> 3) ^ (r & 7)) << 3) + (c & 7)] = (f16)(acc[i][j][e] * 0.125f);
        }
  }
  __syncthreads();

  // phase 2: softmax, register-resident. thread t: row t>>3, 16 chunks (t&7)+8q
  const int r2 = tid >> 3;
  f16* Prow = P + (r2 << 10);
  const int rx = r2 & 7;
  f16x8 vv[16];
  float mrow = -1e30f;
#pragma unroll
  for (int q = 0; q < 16; ++q) {
    const int c = (tid & 7) + (q << 3);
    vv[q] = *(const f16x8*)(Prow + ((c ^ rx) << 3));
#pragma unroll
    for (int e = 0; e < 8; ++e) mrow = fmaxf(mrow, (float)vv[q][e]);
  }
  mrow = fmaxf(mrow, __shfl_xor(mrow, 1));
  mrow = fmaxf(mrow, __shfl_xor(mrow, 2));
  mrow = fmaxf(mrow, __shfl_xor(mrow, 4));
  float ssum = 0.f;
#pragma unroll
  for (int q = 0; q < 16; ++q) {
#pragma unroll
    for (int e = 0; e < 8; ++e) {
      const float ev = __expf((float)vv[q][e] - mrow);
      ssum += ev;
      vv[q][e] = (f16)ev;
    }
  }
  ssum += __shfl_xor(ssum, 1);
  ssum += __shfl_xor(ssum, 2);
  ssum += __shfl_xor(ssum, 4);
  const float inv = 1.0f / ssum;
  float* Aout = attn + ((size_t)bh << 20) + ((size_t)(m0 + r2) << 10);
#pragma unroll
  for (int q = 0; q < 16; ++q) {
    const int c = (tid & 7) + (q << 3);
    f16x8 nv;
    f32x4 o0, o1;
    o0[0] = (float)vv[q][0] * inv; o0[1] = (float)vv[q][1] * inv;
    o0[2] = (float)vv[q][2] * inv; o0[3] = (float)vv[q][3] * inv;
    o1[0] = (float)vv[q][4] * inv; o1[1] = (float)vv[q][5] * inv;
    o1[2] = (float)vv[q][6] * inv; o1[3] = (float)vv[q][7] * inv;
#pragma unroll
    for (int e = 0; e < 8; ++e) nv[e] = (f16)((float)vv[q][e] * inv);
    __builtin_nontemporal_store(o0, (f32x4*)(Aout + (c << 3)));
    __builtin_nontemporal_store(o1, (f32x4*)(Aout + (c << 3)) + 1);
    *(f16x8*)(Prow + ((c ^ rx) << 3)) = nv;
  }
  __syncthreads();

  // phase 3: y = P @ V, V direct from global (L2-resident)
  const int dc = w << 4;
  f32x4 acc2[2] = {};
#pragma unroll 4
  for (int k0 = 0; k0 < 1024; k0 += 32) {
    const f16x8 bf = *(const f16x8*)(Vt + (size_t)(dc + lr) * 1024 + k0 + lg * 8);
#pragma unroll
    for (int i = 0; i < 2; ++i) {
      const int ra = i * 16 + lr;
      const int ch = (k0 >> 3) + lg;
      const f16x8 af = *(const f16x8*)(P + (ra << 10) + ((ch ^ (ra & 7)) << 3));
      acc2[i] = mfma16(af, bf, acc2[i]);
    }
  }
  const int b = bh >> 4, h = bh & 15;
#pragma unroll
  for (int i = 0; i < 2; ++i)
#pragma unroll
    for (int e = 0; e < 4; ++e) {
      const int rloc = i * 16 + (lg << 2) + e;
      y2[(size_t)(b * 1024 + m0 + rloc) * 1024 + (h << 6) + dc + lr] = (f16)acc2[i][e];
    }
}

// ---------------- proj: xmid = y2 @ wproj^T + bproj + x ----------------
__global__ __launch_bounds__(256) void k_proj(const f16* __restrict__ y2,
                                              const f16* __restrict__ wp,
                                              const float* __restrict__ bproj,
                                              const float* __restrict__ x,
                                              float* __restrict__ xmid)
{
  __shared__ __align__(16) f16 As[8192], Bs[8192];
  f32x4 acc[4][4] = {};
  nt_core64(y2 + (size_t)blockIdx.x * 128 * 1024, wp + (size_t)blockIdx.y * 128 * 1024,
            1024, 1024, 1024, As, Bs, acc);
  const int tid = threadIdx.x, lane = tid & 63, w = tid >> 6;
  const int r0 = blockIdx.x * 128 + ((w >> 1) << 6) + ((lane >> 4) << 2);
  const int c0 = blockIdx.y * 128 + ((w & 1) << 6) + (lane & 15);
#pragma unroll
  for (int i = 0; i < 4; ++i)
#pragma unroll
    for (int j = 0; j < 4; ++j) {
      const int c = c0 + j * 16;
      const float bias = bproj[c];
#pragma unroll
      for (int e = 0; e < 4; ++e) {
        const size_t idx = (size_t)(r0 + i * 16 + e) * 1024 + c;
        xmid[idx] = acc[i][j][e] + bias + x[idx];
      }
    }
}

// ---------------- fc1: h = gelu(xn2 @ wfc1^T + bfc1) ----------------
__global__ __launch_bounds__(256) void k_fc1(const f16* __restrict__ xn,
                                             const f16* __restrict__ wf,
                                             const float* __restrict__ bfc1,
                                             f16* __restrict__ hb)
{
  __shared__ __align__(16) f16 As[8192], Bs[8192];
  f32x4 acc[4][4] = {};
  nt_core64(xn + (size_t)blockIdx.x * 128 * 1024, wf + (size_t)blockIdx.y * 128 * 1024,
            1024, 1024, 1024, As, Bs, acc);
  const int tid = threadIdx.x, lane = tid & 63, w = tid >> 6;
  const int r0 = blockIdx.x * 128 + ((w >> 1) << 6) + ((lane >> 4) << 2);
  const int c0 = blockIdx.y * 128 + ((w & 1) << 6) + (lane & 15);
#pragma unroll
  for (int i = 0; i < 4; ++i)
#pragma unroll
    for (int j = 0; j < 4; ++j) {
      const int c = c0 + j * 16;
      const float bias = bfc1[c];
#pragma unroll
      for (int e = 0; e < 4; ++e) {
        const float t = acc[i][j][e] + bias;
        const float ge = 0.5f * t * (1.0f + erff(t * 0.70710678118654752f));
        hb[(size_t)(r0 + i * 16 + e) * 4096 + c] = (f16)ge;
      }
    }
}

// ---------------- fc2: out = h @ wfc2^T + bfc2 + xmid ----------------
__global__ __launch_bounds__(256) void k_fc2(const f16* __restrict__ hb,
                                             const f16* __restrict__ wf,
                                             const float* __restrict__ bfc2,
                                             const float* __restrict__ xmid,
                                             float* __restrict__ out)
{
  __shared__ __align__(16) f16 As[8192], Bs[8192];
  f32x4 acc[4][4] = {};
  nt_core64(hb + (size_t)blockIdx.x * 128 * 4096, wf + (size_t)blockIdx.y * 128 * 4096,
            4096, 4096, 4096, As, Bs, acc);
  const int tid = threadIdx.x, lane = tid & 63, w = tid >> 6;
  const int r0 = blockIdx.x * 128 + ((w >> 1) << 6) + ((lane >> 4) << 2);
  const int c0 = blockIdx.y * 128 + ((w & 1) << 6) + (lane & 15);
#pragma unroll
  for (int i = 0; i < 4; ++i)
#pragma unroll
    for (int j = 0; j < 4; ++j) {
      const int c = c0 + j * 16;
      const float bias = bfc2[c];
#pragma unroll
      for (int e = 0; e < 4; ++e) {
        const size_t idx = (size_t)(r0 + i * 16 + e) * 1024 + c;
        out[idx] = acc[i][j][e] + bias + xmid[idx];
      }
    }
}

extern "C" void kernel_launch(void* const* d_in, const int* in_sizes, int n_in,
                              void* d_out, int out_size, void* d_ws, size_t ws_size,
                              hipStream_t stream)
{
  const float* x     = (const float*)d_in[0];
  const float* ln1g  = (const float*)d_in[1];
  const float* ln1b  = (const float*)d_in[2];
  const float* wqkv  = (const float*)d_in[3];
  const float* wproj = (const float*)d_in[4];
  const float* bproj = (const float*)d_in[5];
  const float* ln2g  = (const float*)d_in[6];
  const float* ln2b  = (const float*)d_in[7];
  const float* wfc1  = (const float*)d_in[8];
  const float* bfc1  = (const float*)d_in[9];
  const float* wfc2  = (const float*)d_in[10];
  const float* bfc2  = (const float*)d_in[11];

  char* ws = (char*)d_ws;
  f16* wqkv_h  = (f16*)(ws);                    //  6 MB  (contiguous cvt dest)
  f16* wproj_h = (f16*)(ws + 6291456);          //  2 MB
  f16* wfc1_h  = (f16*)(ws + 8388608);          //  8 MB
  f16* wfc2_h  = (f16*)(ws + 16777216);         //  8 MB
  f16* xn      = (f16*)(ws + 25165824);         // 16 MB (xn1, reused as xn2)
  f16* qb      = (f16*)(ws + 41943040);         // 16 MB
  f16* kb      = (f16*)(ws + 58720256);         // 16 MB
  f16* vT      = (f16*)(ws + 75497472);         // 16 MB
  f16* y2      = (f16*)(ws + 92274688);         // 16 MB
  float* xmid  = (float*)(ws + 109051904);      // 32 MB
  f16* hb      = (f16*)(ws + 41943040);         // 64 MB, aliases qb..y2 (dead by fc1)

  float* out_x = (float*)d_out;
  float* attn  = (float*)d_out + 8388608;

  k_cvtall<<<12288, 256, 0, stream>>>(wqkv, wproj, wfc1, wfc2, wqkv_h);
  k_ln<<<8192, 256, 0, stream>>>(x, ln1g, ln1b, xn);
  k_qkv<<<dim3(64, 24), 256, 0, stream>>>(xn, wqkv_h, qb, kb, vT);
  k_attn<<<dim3(32, 128), 256, 0, stream>>>(qb, kb, vT, attn, y2);
  k_proj<<<dim3(64, 8), 256, 0, stream>>>(y2, wproj_h, bproj, x, xmid);
  k_ln<<<8192, 256, 0, stream>>>(xmid, ln2g, ln2b, xn);
  k_fc1<<<dim3(64, 32), 256, 0, stream>>>(xn, wfc1_h, bfc1, hb);
  k_fc2<<<dim3(64, 8), 256, 0, stream>>>(hb, wfc2_h, bfc2, xmid, out_x);
}

// Round 6
// 502.029 us; speedup vs baseline: 1.6979x; 1.0438x over previous
//
#include <hip/hip_runtime.h>
#include <cstdint>
#include <math.h>

// Transformer block: LN1 -> QKV -> fused MHA (attn probs = output[1]) -> proj+res
//                    -> LN2 -> GELU MLP + res -> output[0]
// GEMMs: fp16 MFMA 16x16x32, 128x128 tiles, BK=64, global_load_lds width-16
// staging, XOR chunk swizzle (pre-swizzled global source + swizzled ds_read).

typedef _Float16 f16;
typedef _Float16 f16x4 __attribute__((ext_vector_type(4)));
typedef _Float16 f16x8 __attribute__((ext_vector_type(8)));
typedef float f32x4 __attribute__((ext_vector_type(4)));

#define DEV static __device__ __forceinline__

DEV void gload16(const void* g, void* l) {
  __builtin_amdgcn_global_load_lds(
      (__attribute__((address_space(1))) void*)(uintptr_t)g,
      (__attribute__((address_space(3))) void*)(uintptr_t)l, 16, 0, 0);
}

DEV f32x4 mfma16(f16x8 a, f16x8 b, f32x4 c) {
  return __builtin_amdgcn_mfma_f32_16x16x32_f16(a, b, c, 0, 0, 0);
}

// gelu via Abramowitz-Stegun 7.1.26 erf (|err| <= 1.5e-7), branchless single path
DEV float gelu_f(float v) {
  const float a = fabsf(v) * 0.70710678118654752f;
  const float t = 1.0f / (1.0f + 0.3275911f * a);
  const float p = t * (0.254829592f + t * (-0.284496736f + t * (1.421413741f +
                  t * (-1.453152027f + t * 1.061405429f))));
  const float e = p * __expf(-a * a);          // = 1 - erf(a), a >= 0
  const float erfv = v >= 0.f ? (1.f - e) : (e - 1.f);
  return 0.5f * v * (1.0f + erfv);
}

// ===== 128x128 NT GEMM core, BK=64: C_tile = A[128,K] * B[128,K]^T =========
DEV void nt_core64(const f16* __restrict__ A, const f16* __restrict__ B,
                   size_t lda, size_t ldb, int K, f16* As, f16* Bs,
                   f32x4 acc[4][4])
{
  const int tid  = threadIdx.x;
  const int lane = tid & 63;
  const int w    = tid >> 6;
  const int wm   = (w >> 1) << 6;
  const int wn   = (w & 1) << 6;
  const int frow = lane & 15;
  const int lg   = lane >> 4;

  const int srow0 = w * 32 + (lane >> 3);
  const int scol  = ((lane & 7) ^ ((lane >> 3) & 7)) << 3;
  const f16* Ab = A + (size_t)srow0 * lda + scol;
  const f16* Bb = B + (size_t)srow0 * ldb + scol;
  f16* la = As + w * 2048 + lane * 8;   // + L*512
  f16* lb = Bs + w * 2048 + lane * 8;

  for (int k0 = 0; k0 < K; k0 += 64) {
#pragma unroll
    for (int L = 0; L < 4; ++L)
      gload16(Ab + (size_t)(L * 8) * lda + k0, la + L * 512);
#pragma unroll
    for (int L = 0; L < 4; ++L)
      gload16(Bb + (size_t)(L * 8) * ldb + k0, lb + L * 512);
    __syncthreads();
#pragma unroll
    for (int kc = 0; kc < 2; ++kc) {
      f16x8 af[4], bf[4];
#pragma unroll
      for (int i = 0; i < 4; ++i) {
        const int ra = wm + i * 16 + frow;
        const int rb = wn + i * 16 + frow;
        af[i] = *(const f16x8*)(As + ra * 64 + ((((kc << 2) + lg) ^ (ra & 7)) << 3));
        bf[i] = *(const f16x8*)(Bs + rb * 64 + ((((kc << 2) + lg) ^ (rb & 7)) << 3));
      }
#pragma unroll
      for (int i = 0; i < 4; ++i)
#pragma unroll
        for (int j = 0; j < 4; ++j)
          acc[i][j] = mfma16(af[i], bf[j], acc[i][j]);
    }
    __syncthreads();
  }
}

// ------- fused: fp32->fp16 weight convert (blocks 0..12287) + LN1 (rest) ----
__global__ __launch_bounds__(256) void k_cvt_ln(const float* __restrict__ s0,
                                                const float* __restrict__ s1,
                                                const float* __restrict__ s2,
                                                const float* __restrict__ s3,
                                                f16* __restrict__ wout,
                                                const float* __restrict__ xin,
                                                const float* __restrict__ g,
                                                const float* __restrict__ bb,
                                                f16* __restrict__ xnout)
{
  __shared__ float red[8];
  const int tid = threadIdx.x;
  if (blockIdx.x < 12288) {
    const int i = blockIdx.x * 256 + tid;    // float4 index
    const float* src;
    int off;
    if (i < 786432)       { src = s0; off = 0; }
    else if (i < 1048576) { src = s1; off = 786432; }
    else if (i < 2097152) { src = s2; off = 1048576; }
    else                  { src = s3; off = 2097152; }
    const float4 f = ((const float4*)src)[i - off];
    f16x4 o; o[0] = (f16)f.x; o[1] = (f16)f.y; o[2] = (f16)f.z; o[3] = (f16)f.w;
    ((f16x4*)wout)[i] = o;
    return;
  }
  const size_t row = blockIdx.x - 12288;
  const float4 v = ((const float4*)(xin + row * 1024))[tid];
  float s  = v.x + v.y + v.z + v.w;
  float sq = v.x * v.x + v.y * v.y + v.z * v.z + v.w * v.w;
#pragma unroll
  for (int off = 32; off > 0; off >>= 1) { s += __shfl_xor(s, off); sq += __shfl_xor(sq, off); }
  if ((tid & 63) == 0) { red[tid >> 6] = s; red[4 + (tid >> 6)] = sq; }
  __syncthreads();
  s  = red[0] + red[1] + red[2] + red[3];
  sq = red[4] + red[5] + red[6] + red[7];
  const float mu = s * (1.0f / 1024.0f);
  const float rs = rsqrtf(sq * (1.0f / 1024.0f) - mu * mu + 1e-5f);
  const float4 gg = ((const float4*)g)[tid];
  const float4 bv = ((const float4*)bb)[tid];
  f16x4 o;
  o[0] = (f16)((v.x - mu) * rs * gg.x + bv.x);
  o[1] = (f16)((v.y - mu) * rs * gg.y + bv.y);
  o[2] = (f16)((v.z - mu) * rs * gg.z + bv.z);
  o[3] = (f16)((v.w - mu) * rs * gg.w + bv.w);
  ((f16x4*)(xnout + row * 1024))[tid] = o;
}

// ---------------- LayerNorm (1024 cols, 1 row/block) ----------------
__global__ __launch_bounds__(256) void k_ln(const float* __restrict__ xin,
                                            const float* __restrict__ g,
                                            const float* __restrict__ bb,
                                            f16* __restrict__ out)
{
  __shared__ float red[8];
  const int tid = threadIdx.x;
  const size_t row = blockIdx.x;
  const float4 v = ((const float4*)(xin + row * 1024))[tid];
  float s  = v.x + v.y + v.z + v.w;
  float sq = v.x * v.x + v.y * v.y + v.z * v.z + v.w * v.w;
#pragma unroll
  for (int off = 32; off > 0; off >>= 1) { s += __shfl_xor(s, off); sq += __shfl_xor(sq, off); }
  if ((tid & 63) == 0) { red[tid >> 6] = s; red[4 + (tid >> 6)] = sq; }
  __syncthreads();
  s  = red[0] + red[1] + red[2] + red[3];
  sq = red[4] + red[5] + red[6] + red[7];
  const float mu = s * (1.0f / 1024.0f);
  const float rs = rsqrtf(sq * (1.0f / 1024.0f) - mu * mu + 1e-5f);
  const float4 gg = ((const float4*)g)[tid];
  const float4 bv = ((const float4*)bb)[tid];
  f16x4 o;
  o[0] = (f16)((v.x - mu) * rs * gg.x + bv.x);
  o[1] = (f16)((v.y - mu) * rs * gg.y + bv.y);
  o[2] = (f16)((v.z - mu) * rs * gg.z + bv.z);
  o[3] = (f16)((v.w - mu) * rs * gg.w + bv.w);
  ((f16x4*)(out + row * 1024))[tid] = o;
}

// ---------------- QKV GEMM: [8192,1024] x [3072,1024]^T ----------------
__global__ __launch_bounds__(256) void k_qkv(const f16* __restrict__ xn,
                                             const f16* __restrict__ wq,
                                             f16* __restrict__ qb, f16* __restrict__ kb,
                                             f16* __restrict__ vT)
{
  __shared__ __align__(16) f16 As[8192], Bs[8192];
  f32x4 acc[4][4] = {};
  const int bm = blockIdx.x, bn = blockIdx.y;
  nt_core64(xn + (size_t)bm * 128 * 1024, wq + (size_t)bn * 128 * 1024,
            1024, 1024, 1024, As, Bs, acc);
  const int tid = threadIdx.x, lane = tid & 63, w = tid >> 6;
  const int r0 = bm * 128 + ((w >> 1) << 6) + ((lane >> 4) << 2);
  const int c0 = bn * 128 + ((w & 1) << 6);
  const int sec = (bn * 128) >> 10;
#pragma unroll
  for (int i = 0; i < 4; ++i) {
#pragma unroll
    for (int j = 0; j < 4; ++j) {
      const int o = c0 + j * 16 + (lane & 15);
      const int h = (o & 1023) >> 6, d = o & 63;
#pragma unroll
      for (int e = 0; e < 4; ++e) {
        const int m = r0 + i * 16 + e;
        const int b = m >> 10, n = m & 1023;
        const int bh = (b << 4) + h;
        const f16 val = (f16)acc[i][j][e];
        if (sec == 0)      qb[((size_t)bh * 1024 + n) * 64 + d] = val;
        else if (sec == 1) kb[((size_t)bh * 1024 + n) * 64 + d] = val;
        else               vT[((size_t)bh * 64 + d) * 1024 + n] = val;
      }
    }
  }
}

// ---------------- fused attention: S=QK^T*scale, softmax, attn out, y=PV ------
// LDS P[32][1024] fp16, chunk-swizzled: (r,c) at r*1024 + (((c>>3)^(r&7))<<3)+(c&7)
// XCD-chunked block swizzle: each XCD owns 16 whole heads -> K/V L2-resident.
__global__ __launch_bounds__(256) void k_attn(const f16* __restrict__ qb,
                                              const f16* __restrict__ kb,
                                              const f16* __restrict__ vT,
                                              float* __restrict__ attn,
                                              f16* __restrict__ y2)
{
  __shared__ __align__(16) f16 P[32 * 1024];   // exactly 64 KB
  const int tid = threadIdx.x, lane = tid & 63, w = tid >> 6;
  const int lr = lane & 15, lg = lane >> 4;
  const int flat = blockIdx.y * 32 + blockIdx.x;        // 4096 blocks
  const int id2 = (flat & 7) * 512 + (flat >> 3);       // bijective, 8 chunks
  const int bh = id2 >> 5;
  const int m0 = (id2 & 31) * 32;
  const f16* Qb = qb + ((size_t)bh << 16);
  const f16* Kb = kb + ((size_t)bh << 16);
  const f16* Vt = vT + ((size_t)bh << 16);

  f16x8 qf[2][2];
#pragma unroll
  for (int i = 0; i < 2; ++i)
#pragma unroll
    for (int ks = 0; ks < 2; ++ks)
      qf[i][ks] = *(const f16x8*)(Qb + (size_t)(m0 + i * 16 + lr) * 64 + ks * 32 + lg * 8);

  // phase 1: S -> P_lds (fp16, scaled)
  for (int cc = 0; cc < 4; ++cc) {
    const int cb = (w << 8) + (cc << 6);
    f16x8 bf[4][2];
#pragma unroll
    for (int j = 0; j < 4; ++j)
#pragma unroll
      for (int ks = 0; ks < 2; ++ks)
        bf[j][ks] = *(const f16x8*)(Kb + (size_t)(cb + j * 16 + lr) * 64 + ks * 32 + lg * 8);
    f32x4 acc[2][4] = {};
#pragma unroll
    for (int i = 0; i < 2; ++i)
#pragma unroll
      for (int j = 0; j < 4; ++j) {
        acc[i][j] = mfma16(qf[i][0], bf[j][0], acc[i][j]);
        acc[i][j] = mfma16(qf[i][1], bf[j][1], acc[i][j]);
      }
#pragma unroll
    for (int i = 0; i < 2; ++i)
#pragma unroll
      for (int j = 0; j < 4; ++j)
#pragma unroll
        for (int e = 0; e < 4; ++e) {
          const int r = i * 16 + (lg << 2) + e;
          const int c = cb + j * 16 + lr;
          P[(r << 10) + (((c >> 3) ^ (r & 7)) << 3) + (c & 7)] = (f16)(acc[i][j][e] * 0.125f);
        }
  }
  __syncthreads();

  // phase 2: softmax, register-resident. thread t: row t>>3, 16 chunks (t&7)+8q
  const int r2 = tid >> 3;
  f16* Prow = P + (r2 << 10);
  const int rx = r2 & 7;
  f16x8 vv[16];
  float mrow = -1e30f;
#pragma unroll
  for (int q = 0; q < 16; ++q) {
    const int c = (tid & 7) + (q << 3);
    vv[q] = *(const f16x8*)(Prow + ((c ^ rx) << 3));
#pragma unroll
    for (int e = 0; e < 8; ++e) mrow = fmaxf(mrow, (float)vv[q][e]);
  }
  mrow = fmaxf(mrow, __shfl_xor(mrow, 1));
  mrow = fmaxf(mrow, __shfl_xor(mrow, 2));
  mrow = fmaxf(mrow, __shfl_xor(mrow, 4));
  float ssum = 0.f;
#pragma unroll
  for (int q = 0; q < 16; ++q) {
#pragma unroll
    for (int e = 0; e < 8; ++e) {
      const float ev = __expf((float)vv[q][e] - mrow);
      ssum += ev;
      vv[q][e] = (f16)ev;
    }
  }
  ssum += __shfl_xor(ssum, 1);
  ssum += __shfl_xor(ssum, 2);
  ssum += __shfl_xor(ssum, 4);
  const float inv = 1.0f / ssum;
  float* Aout = attn + ((size_t)bh << 20) + ((size_t)(m0 + r2) << 10);
#pragma unroll
  for (int q = 0; q < 16; ++q) {
    const int c = (tid & 7) + (q << 3);
    f16x8 nv;
    f32x4 o0, o1;
    o0[0] = (float)vv[q][0] * inv; o0[1] = (float)vv[q][1] * inv;
    o0[2] = (float)vv[q][2] * inv; o0[3] = (float)vv[q][3] * inv;
    o1[0] = (float)vv[q][4] * inv; o1[1] = (float)vv[q][5] * inv;
    o1[2] = (float)vv[q][6] * inv; o1[3] = (float)vv[q][7] * inv;
#pragma unroll
    for (int e = 0; e < 8; ++e) nv[e] = (f16)((float)vv[q][e] * inv);
    __builtin_nontemporal_store(o0, (f32x4*)(Aout + (c << 3)));
    __builtin_nontemporal_store(o1, (f32x4*)(Aout + (c << 3)) + 1);
    *(f16x8*)(Prow + ((c ^ rx) << 3)) = nv;
  }
  __syncthreads();

  // phase 3: y = P @ V, V direct from global (L2-resident)
  const int dc = w << 4;
  f32x4 acc2[2] = {};
#pragma unroll 4
  for (int k0 = 0; k0 < 1024; k0 += 32) {
    const f16x8 bf = *(const f16x8*)(Vt + (size_t)(dc + lr) * 1024 + k0 + lg * 8);
#pragma unroll
    for (int i = 0; i < 2; ++i) {
      const int ra = i * 16 + lr;
      const int ch = (k0 >> 3) + lg;
      const f16x8 af = *(const f16x8*)(P + (ra << 10) + ((ch ^ (ra & 7)) << 3));
      acc2[i] = mfma16(af, bf, acc2[i]);
    }
  }
  const int b = bh >> 4, h = bh & 15;
#pragma unroll
  for (int i = 0; i < 2; ++i)
#pragma unroll
    for (int e = 0; e < 4; ++e) {
      const int rloc = i * 16 + (lg << 2) + e;
      y2[(size_t)(b * 1024 + m0 + rloc) * 1024 + (h << 6) + dc + lr] = (f16)acc2[i][e];
    }
}

// ---------------- proj: xmid = y2 @ wproj^T + bproj + x ----------------
__global__ __launch_bounds__(256) void k_proj(const f16* __restrict__ y2,
                                              const f16* __restrict__ wp,
                                              const float* __restrict__ bproj,
                                              const float* __restrict__ x,
                                              float* __restrict__ xmid)
{
  __shared__ __align__(16) f16 As[8192], Bs[8192];
  f32x4 acc[4][4] = {};
  nt_core64(y2 + (size_t)blockIdx.x * 128 * 1024, wp + (size_t)blockIdx.y * 128 * 1024,
            1024, 1024, 1024, As, Bs, acc);
  const int tid = threadIdx.x, lane = tid & 63, w = tid >> 6;
  const int r0 = blockIdx.x * 128 + ((w >> 1) << 6) + ((lane >> 4) << 2);
  const int c0 = blockIdx.y * 128 + ((w & 1) << 6) + (lane & 15);
#pragma unroll
  for (int i = 0; i < 4; ++i)
#pragma unroll
    for (int j = 0; j < 4; ++j) {
      const int c = c0 + j * 16;
      const float bias = bproj[c];
#pragma unroll
      for (int e = 0; e < 4; ++e) {
        const size_t idx = (size_t)(r0 + i * 16 + e) * 1024 + c;
        xmid[idx] = acc[i][j][e] + bias + x[idx];
      }
    }
}

// ---------------- fc1: h = gelu(xn2 @ wfc1^T + bfc1) ----------------
__global__ __launch_bounds__(256) void k_fc1(const f16* __restrict__ xn,
                                             const f16* __restrict__ wf,
                                             const float* __restrict__ bfc1,
                                             f16* __restrict__ hb)
{
  __shared__ __align__(16) f16 As[8192], Bs[8192];
  f32x4 acc[4][4] = {};
  nt_core64(xn + (size_t)blockIdx.x * 128 * 1024, wf + (size_t)blockIdx.y * 128 * 1024,
            1024, 1024, 1024, As, Bs, acc);
  const int tid = threadIdx.x, lane = tid & 63, w = tid >> 6;
  const int r0 = blockIdx.x * 128 + ((w >> 1) << 6) + ((lane >> 4) << 2);
  const int c0 = blockIdx.y * 128 + ((w & 1) << 6) + (lane & 15);
#pragma unroll
  for (int i = 0; i < 4; ++i)
#pragma unroll
    for (int j = 0; j < 4; ++j) {
      const int c = c0 + j * 16;
      const float bias = bfc1[c];
#pragma unroll
      for (int e = 0; e < 4; ++e) {
        const float t = acc[i][j][e] + bias;
        hb[(size_t)(r0 + i * 16 + e) * 4096 + c] = (f16)gelu_f(t);
      }
    }
}

// ---------------- fc2: out = h @ wfc2^T + bfc2 + xmid ----------------
__global__ __launch_bounds__(256) void k_fc2(const f16* __restrict__ hb,
                                             const f16* __restrict__ wf,
                                             const float* __restrict__ bfc2,
                                             const float* __restrict__ xmid,
                                             float* __restrict__ out)
{
  __shared__ __align__(16) f16 As[8192], Bs[8192];
  f32x4 acc[4][4] = {};
  nt_core64(hb + (size_t)blockIdx.x * 128 * 4096, wf + (size_t)blockIdx.y * 128 * 4096,
            4096, 4096, 4096, As, Bs, acc);
  const int tid = threadIdx.x, lane = tid & 63, w = tid >> 6;
  const int r0 = blockIdx.x * 128 + ((w >> 1) << 6) + ((lane >> 4) << 2);
  const int c0 = blockIdx.y * 128 + ((w & 1) << 6) + (lane & 15);
#pragma unroll
  for (int i = 0; i < 4; ++i)
#pragma unroll
    for (int j = 0; j < 4; ++j) {
      const int c = c0 + j * 16;
      const float bias = bfc2[c];
#pragma unroll
      for (int e = 0; e < 4; ++e) {
        const size_t idx = (size_t)(r0 + i * 16 + e) * 1024 + c;
        out[idx] = acc[i][j][e] + bias + xmid[idx];
      }
    }
}

extern "C" void kernel_launch(void* const* d_in, const int* in_sizes, int n_in,
                              void* d_out, int out_size, void* d_ws, size_t ws_size,
                              hipStream_t stream)
{
  const float* x     = (const float*)d_in[0];
  const float* ln1g  = (const float*)d_in[1];
  const float* ln1b  = (const float*)d_in[2];
  const float* wqkv  = (const float*)d_in[3];
  const float* wproj = (const float*)d_in[4];
  const float* bproj = (const float*)d_in[5];
  const float* ln2g  = (const float*)d_in[6];
  const float* ln2b  = (const float*)d_in[7];
  const float* wfc1  = (const float*)d_in[8];
  const float* bfc1  = (const float*)d_in[9];
  const float* wfc2  = (const float*)d_in[10];
  const float* bfc2  = (const float*)d_in[11];

  char* ws = (char*)d_ws;
  f16* wqkv_h  = (f16*)(ws);                    //  6 MB  (contiguous cvt dest)
  f16* wproj_h = (f16*)(ws + 6291456);          //  2 MB
  f16* wfc1_h  = (f16*)(ws + 8388608);          //  8 MB
  f16* wfc2_h  = (f16*)(ws + 16777216);         //  8 MB
  f16* xn      = (f16*)(ws + 25165824);         // 16 MB (xn1, reused as xn2)
  f16* qb      = (f16*)(ws + 41943040);         // 16 MB
  f16* kb      = (f16*)(ws + 58720256);         // 16 MB
  f16* vT      = (f16*)(ws + 75497472);         // 16 MB
  f16* y2      = (f16*)(ws + 92274688);         // 16 MB
  float* xmid  = (float*)(ws + 109051904);      // 32 MB
  f16* hb      = (f16*)(ws + 41943040);         // 64 MB, aliases qb..y2 (dead by fc1)

  float* out_x = (float*)d_out;
  float* attn  = (float*)d_out + 8388608;

  k_cvt_ln<<<12288 + 8192, 256, 0, stream>>>(wqkv, wproj, wfc1, wfc2, wqkv_h,
                                             x, ln1g, ln1b, xn);
  k_qkv<<<dim3(64, 24), 256, 0, stream>>>(xn, wqkv_h, qb, kb, vT);
  k_attn<<<dim3(32, 128), 256, 0, stream>>>(qb, kb, vT, attn, y2);
  k_proj<<<dim3(64, 8), 256, 0, stream>>>(y2, wproj_h, bproj, x, xmid);
  k_ln<<<8192, 256, 0, stream>>>(xmid, ln2g, ln2b, xn);
  k_fc1<<<dim3(64, 32), 256, 0, stream>>>(xn, wfc1_h, bfc1, hb);
  k_fc2<<<dim3(64, 8), 256, 0, stream>>>(hb, wfc2_h, bfc2, xmid, out_x);
}